// Round 5
// baseline (19346.936 us; speedup 1.0000x reference)
//
#include <hip/hip_runtime.h>
#include <stdint.h>

#define NB 65536      // B rows
#define ND 256        // D
#define NK 2048       // K
#define NL 4          // L
#define THRM 0.012f   // accept margin for fp16 screening (error RMS ~6.4e-4, 18 sigma)

typedef _Float16 v8h __attribute__((ext_vector_type(8)));   // 8 fp16 (4 VGPR)
typedef __attribute__((ext_vector_type(4))) float v4f;      // MFMA acc
typedef unsigned long long ull;

// ---------------- zero the per-level uncertain counters ----------------
__global__ void k_zero(int* __restrict__ cnt) {
    if (threadIdx.x < NL) cnt[threadIdx.x] = 0;
}

// ---------------- e2: numpy-pairwise sum of emb^2 per row (validated r2) ----------------
__global__ void k_e2(const float* __restrict__ cb, float* __restrict__ e2) {
    __shared__ float tile[32 * 260];
    const int rowbase = blockIdx.x * 32;
    const float4* cb4 = (const float4*)(cb + (size_t)rowbase * ND);
    for (int it = 0; it < 32; ++it) {
        float4 v = cb4[it * 64 + threadIdx.x];
        *(float4*)&tile[it * 260 + threadIdx.x * 4] = v;
    }
    __syncthreads();
    if (threadIdx.x < 32) {
        const float* a = &tile[threadIdx.x * 260];
        float halves[2];
        for (int h = 0; h < 2; ++h) {
            const float* p = a + h * 128;
            float r8[8];
            #pragma unroll
            for (int j = 0; j < 8; ++j) r8[j] = __fmul_rn(p[j], p[j]);
            for (int i = 8; i < 128; i += 8) {
                #pragma unroll
                for (int j = 0; j < 8; ++j) r8[j] = __fadd_rn(r8[j], __fmul_rn(p[i + j], p[i + j]));
            }
            halves[h] = __fadd_rn(__fadd_rn(__fadd_rn(r8[0], r8[1]), __fadd_rn(r8[2], r8[3])),
                                  __fadd_rn(__fadd_rn(r8[4], r8[5]), __fadd_rn(r8[6], r8[7])));
        }
        e2[rowbase + threadIdx.x] = __fadd_rn(halves[0], halves[1]);
    }
}

// ---------------- convert codebooks to fp16 fragment-major ----------------
// 16B-unit address: u16 = (k>>4)*512 + (g>>2)*64 + (g&3)*16 + (k&15), g = d>>3
__global__ void k_split16(const float* __restrict__ cb, unsigned short* __restrict__ ehf) {
    const int f = blockIdx.x * 256 + threadIdx.x;     // 0 .. L*K*32
    const int g = f & 31;
    const int k = (f >> 5) & (NK - 1);
    const int l = f >> 16;
    const float* p = cb + ((size_t)(l * NK + k) * ND + g * 8);
    float4 a = *(const float4*)p;
    float4 b = *(const float4*)(p + 4);
    v8h h;
    h[0] = (_Float16)a.x; h[1] = (_Float16)a.y; h[2] = (_Float16)a.z; h[3] = (_Float16)a.w;
    h[4] = (_Float16)b.x; h[5] = (_Float16)b.y; h[6] = (_Float16)b.z; h[7] = (_Float16)b.w;
    const size_t u = (size_t)(k >> 4) * 512 + (g >> 2) * 64 + (g & 3) * 16 + (k & 15);
    *(v8h*)(void*)(ehf + (size_t)l * (NK * ND) + u * 8) = h;
}

// ---------------- pass A: fp16 MFMA screening + best/second argmin, split-K x2 ----------------
// grid 1024: bx&1 = K-half, bx>>1 = 128-row tile. 256 thr = 4 waves x 32 rows.
__global__ __launch_bounds__(256, 3)
void k_passA(const float* __restrict__ residual,
             const float* __restrict__ cb,             // all levels fp32 [L,K,D]
             const unsigned short* __restrict__ ehf,   // level fragment-major fp16
             const float* __restrict__ e2,             // level e2
             const int* __restrict__ idx_hist,         // [L][B]
             ull* __restrict__ pb,                     // [2][B] packed (b1,k1)
             float* __restrict__ ps2,                  // [2][B] second-best
             int level)
{
    __shared__ unsigned short btile[2][8192];          // 2 x 16KB (32 k x 256 d fp16)

    const int tid = threadIdx.x;
    const int w = tid >> 6;
    const int lane = tid & 63;
    const int kloc = lane & 15;
    const int quad = lane >> 4;
    const int half = blockIdx.x & 1;
    const int rowbase = (blockIdx.x >> 1) * 128 + w * 32;

    // A fragments: residual minus previous-level picks (exact fsub chain), fp16
    v8h ah[2][8];
    #pragma unroll
    for (int m = 0; m < 2; ++m) {
        const int row = rowbase + m * 16 + kloc;
        const float* rp = residual + (size_t)row * ND;
        int pk[NL];
        for (int j = 0; j < level; ++j) pk[j] = idx_hist[j * NB + row];
        #pragma unroll
        for (int dc = 0; dc < 8; ++dc) {
            const int d0 = dc * 32 + quad * 8;
            float buf[8];
            *(float4*)&buf[0] = *(const float4*)(rp + d0);
            *(float4*)&buf[4] = *(const float4*)(rp + d0 + 4);
            for (int j = 0; j < level; ++j) {
                const float* qp = cb + ((size_t)(j * NK + pk[j]) * ND + d0);
                #pragma unroll
                for (int c = 0; c < 8; ++c) buf[c] = __fsub_rn(buf[c], qp[c]);
            }
            #pragma unroll
            for (int c = 0; c < 8; ++c) ah[m][dc][c] = (_Float16)buf[c];
        }
    }

    float b1[8], b2[8];
    int k1[8];
    #pragma unroll
    for (int s = 0; s < 8; ++s) { b1[s] = 1e30f; b2[s] = 1e30f; k1[s] = 0; }

    // prefetch pipeline: one tile ahead in regs, one barrier per kt
    const uint4* src = (const uint4*)(ehf + (size_t)half * (1024 * ND));
    uint4 pf[4];
    #pragma unroll
    for (int i = 0; i < 4; ++i) pf[i] = src[i * 256 + tid];           // tile 0
    {
        uint4* dst = (uint4*)&btile[0][0];
        #pragma unroll
        for (int i = 0; i < 4; ++i) dst[i * 256 + tid] = pf[i];
    }
    #pragma unroll
    for (int i = 0; i < 4; ++i) pf[i] = src[1024 + i * 256 + tid];    // tile 1
    __syncthreads();

    #pragma unroll 1
    for (int kt = 0; kt < 32; ++kt) {
        const int b = kt & 1;
        #pragma unroll
        for (int nt = 0; nt < 2; ++nt) {
            const int kglob = half * 1024 + kt * 32 + nt * 16 + kloc;
            const float e2v = e2[kglob];
            v4f a0a = {0.f,0.f,0.f,0.f}, a0b = {0.f,0.f,0.f,0.f};
            v4f a1a = {0.f,0.f,0.f,0.f}, a1b = {0.f,0.f,0.f,0.f};
            #pragma unroll
            for (int dc = 0; dc < 4; ++dc) {
                const v8h bh = *(const v8h*)(void*)&btile[b][((nt * 8 + dc) * 64 + quad * 16 + kloc) * 8];
                a0a = __builtin_amdgcn_mfma_f32_16x16x32_f16(ah[0][dc], bh, a0a, 0, 0, 0);
                a1a = __builtin_amdgcn_mfma_f32_16x16x32_f16(ah[1][dc], bh, a1a, 0, 0, 0);
            }
            #pragma unroll
            for (int dc = 4; dc < 8; ++dc) {
                const v8h bh = *(const v8h*)(void*)&btile[b][((nt * 8 + dc) * 64 + quad * 16 + kloc) * 8];
                a0b = __builtin_amdgcn_mfma_f32_16x16x32_f16(ah[0][dc], bh, a0b, 0, 0, 0);
                a1b = __builtin_amdgcn_mfma_f32_16x16x32_f16(ah[1][dc], bh, a1b, 0, 0, 0);
            }
            #pragma unroll
            for (int reg = 0; reg < 4; ++reg) {
                const float s0 = __fmaf_rn(-2.0f, a0a[reg] + a0b[reg], e2v);
                if (s0 < b1[reg])      { b2[reg] = b1[reg]; b1[reg] = s0; k1[reg] = kglob; }
                else if (s0 < b2[reg]) { b2[reg] = s0; }
                const float s1 = __fmaf_rn(-2.0f, a1a[reg] + a1b[reg], e2v);
                if (s1 < b1[4 + reg])      { b2[4 + reg] = b1[4 + reg]; b1[4 + reg] = s1; k1[4 + reg] = kglob; }
                else if (s1 < b2[4 + reg]) { b2[4 + reg] = s1; }
            }
        }
        // stage tile kt+1 into the buffer consumed at kt-1 (done since last barrier)
        {
            uint4* dst = (uint4*)&btile[1 - b][0];
            #pragma unroll
            for (int i = 0; i < 4; ++i) dst[i * 256 + tid] = pf[i];
        }
        if (kt + 2 < 32) {
            #pragma unroll
            for (int i = 0; i < 4; ++i) pf[i] = src[(size_t)(kt + 2) * 1024 + i * 256 + tid];
        }
        __syncthreads();
    }

    // merge best/second across the 16 lanes of each quad-group
    #pragma unroll
    for (int off = 1; off < 16; off <<= 1) {
        #pragma unroll
        for (int s = 0; s < 8; ++s) {
            float o1 = __shfl_xor(b1[s], off, 16);
            float o2 = __shfl_xor(b2[s], off, 16);
            int   ok = __shfl_xor(k1[s], off, 16);
            float n1 = fminf(b1[s], o1);
            float hi = fmaxf(b1[s], o1);
            float n2 = fminf(fminf(b2[s], o2), hi);
            int   nk = (o1 < b1[s]) ? ok : k1[s];
            b1[s] = n1; b2[s] = n2; k1[s] = nk;
        }
    }
    if (kloc == 0) {
        #pragma unroll
        for (int s = 0; s < 8; ++s) {
            const int m = s >> 2, reg = s & 3;
            const int row = rowbase + m * 16 + quad * 4 + reg;
            pb[(size_t)half * NB + row] = ((ull)__float_as_uint(b1[s]) << 32) | (ull)(unsigned)k1[s];
            ps2[(size_t)half * NB + row] = b2[s];
        }
    }
}

// ---------------- merge K-halves, emit codes, build uncertain list ----------------
__global__ void k_margin(const ull* __restrict__ pb, const float* __restrict__ ps2,
                         int* __restrict__ idx_l, float* __restrict__ codes,
                         int* __restrict__ ulist, int* __restrict__ cnt, int level)
{
    const int row = blockIdx.x * 256 + threadIdx.x;
    const ull pa = pb[row], pbh = pb[NB + row];
    const ull bmin = (pa < pbh) ? pa : pbh;
    const float f1a = __uint_as_float((unsigned)(pa >> 32));
    const float f1b = __uint_as_float((unsigned)(pbh >> 32));
    const float b2 = fminf(fminf(ps2[row], ps2[NB + row]), fmaxf(f1a, f1b));
    const int k = (int)(bmin & 0xffffffffull);
    idx_l[row] = k;
    codes[(size_t)row * NL + level] = (float)k;
    const float b1 = __uint_as_float((unsigned)(bmin >> 32));
    if (b2 - b1 <= THRM) {
        int p = atomicAdd(cnt, 1);
        ulist[p] = row;
    }
}

// ---------------- rerank stage 1: exact scores (bit-exact validated path) ----------------
__global__ __launch_bounds__(256)
void k_rr1(const float* __restrict__ residual,
           const float* __restrict__ cb,       // all levels
           const float* __restrict__ emb,      // level [K, D]
           const float* __restrict__ e2,       // level e2
           const int* __restrict__ idx_hist,
           const int* __restrict__ ulist,
           const int* __restrict__ cnt,
           ull* __restrict__ partial,          // [(NB+16)][32]
           int level)
{
    __shared__ float embL[64 * 260];
    __shared__ float resL[16 * 260];
    __shared__ float x2s[16];
    __shared__ int   urows[16];
    __shared__ ull   redM[16][17];

    const int t = threadIdx.x;
    const int ks = blockIdx.x & 31;
    const int rt0 = blockIdx.x >> 5;
    const int n = *cnt;
    const int nrt = (n + 15) >> 4;
    if (rt0 >= nrt) return;

    #pragma unroll
    for (int i = 0; i < 16; ++i) {
        const int fi = t + 256 * i;
        const int r = fi >> 6, q = fi & 63;
        *(float4*)&embL[r * 260 + q * 4] = *(const float4*)&emb[(size_t)(ks * 64 + r) * ND + q * 4];
    }
    const int row = t & 15;
    const int kg = t >> 4;
    float e2r[4];
    #pragma unroll
    for (int j = 0; j < 4; ++j) e2r[j] = e2[ks * 64 + kg * 4 + j];

    for (int rt = rt0; rt < nrt; rt += 64) {
        __syncthreads();
        if (t < 16) {
            const int i = rt * 16 + t;
            urows[t] = ulist[(i < n) ? i : rt * 16];
        }
        __syncthreads();
        #pragma unroll
        for (int i = 0; i < 4; ++i) {
            const int fi = t + 256 * i;
            const int r = fi >> 6, q = fi & 63;
            const int ur = urows[r];
            float4 v = ((const float4*)residual)[(size_t)ur * 64 + q];
            for (int j = 0; j < level; ++j) {
                const int kp = idx_hist[j * NB + ur];
                const float4 qv = ((const float4*)cb)[(size_t)(j * NK + kp) * 64 + q];
                v.x = __fsub_rn(v.x, qv.x);
                v.y = __fsub_rn(v.y, qv.y);
                v.z = __fsub_rn(v.z, qv.z);
                v.w = __fsub_rn(v.w, qv.w);
            }
            *(float4*)&resL[r * 260 + q * 4] = v;
        }
        __syncthreads();
        if (t < 16) {
            const float* a = &resL[t * 260];
            float halves[2];
            for (int h = 0; h < 2; ++h) {
                const float* p = a + h * 128;
                float r8[8];
                #pragma unroll
                for (int j = 0; j < 8; ++j) r8[j] = __fmul_rn(p[j], p[j]);
                for (int i = 8; i < 128; i += 8) {
                    #pragma unroll
                    for (int j = 0; j < 8; ++j) r8[j] = __fadd_rn(r8[j], __fmul_rn(p[i + j], p[i + j]));
                }
                halves[h] = __fadd_rn(__fadd_rn(__fadd_rn(r8[0], r8[1]), __fadd_rn(r8[2], r8[3])),
                                      __fadd_rn(__fadd_rn(r8[4], r8[5]), __fadd_rn(r8[6], r8[7])));
            }
            x2s[t] = __fadd_rn(halves[0], halves[1]);
        }
        __syncthreads();

        float d0 = 0.f, d1 = 0.f, d2 = 0.f, d3 = 0.f;
        const float* rp = &resL[row * 260];
        const float* ep = &embL[(kg * 4) * 260];
        #pragma unroll 8
        for (int q = 0; q < 64; ++q) {
            const float4 rv = *(const float4*)&rp[q * 4];
            const float4 e0 = *(const float4*)&ep[q * 4];
            const float4 e1 = *(const float4*)&ep[260 + q * 4];
            const float4 ee2 = *(const float4*)&ep[520 + q * 4];
            const float4 e3 = *(const float4*)&ep[780 + q * 4];
            d0 = __fmaf_rn(rv.x, e0.x, d0); d0 = __fmaf_rn(rv.y, e0.y, d0);
            d0 = __fmaf_rn(rv.z, e0.z, d0); d0 = __fmaf_rn(rv.w, e0.w, d0);
            d1 = __fmaf_rn(rv.x, e1.x, d1); d1 = __fmaf_rn(rv.y, e1.y, d1);
            d1 = __fmaf_rn(rv.z, e1.z, d1); d1 = __fmaf_rn(rv.w, e1.w, d1);
            d2 = __fmaf_rn(rv.x, ee2.x, d2); d2 = __fmaf_rn(rv.y, ee2.y, d2);
            d2 = __fmaf_rn(rv.z, ee2.z, d2); d2 = __fmaf_rn(rv.w, ee2.w, d2);
            d3 = __fmaf_rn(rv.x, e3.x, d3); d3 = __fmaf_rn(rv.y, e3.y, d3);
            d3 = __fmaf_rn(rv.z, e3.z, d3); d3 = __fmaf_rn(rv.w, e3.w, d3);
        }

        const float x2v = x2s[row];
        const int kb = ks * 64 + kg * 4;
        float s;
        ull best, u;
        s = __fsub_rn(__fadd_rn(x2v, e2r[0]), __fmul_rn(2.0f, d0));
        best = ((ull)__float_as_uint(s) << 32) | (ull)(kb + 0);
        s = __fsub_rn(__fadd_rn(x2v, e2r[1]), __fmul_rn(2.0f, d1));
        u = ((ull)__float_as_uint(s) << 32) | (ull)(kb + 1);
        if (u < best) best = u;
        s = __fsub_rn(__fadd_rn(x2v, e2r[2]), __fmul_rn(2.0f, d2));
        u = ((ull)__float_as_uint(s) << 32) | (ull)(kb + 2);
        if (u < best) best = u;
        s = __fsub_rn(__fadd_rn(x2v, e2r[3]), __fmul_rn(2.0f, d3));
        u = ((ull)__float_as_uint(s) << 32) | (ull)(kb + 3);
        if (u < best) best = u;

        redM[row][kg] = best;
        __syncthreads();
        if (t < 16) {
            ull b = redM[t][0];
            #pragma unroll
            for (int g = 1; g < 16; ++g) { const ull v = redM[t][g]; if (v < b) b = v; }
            partial[(size_t)(rt * 16 + t) * 32 + ks] = b;
        }
    }
}

// ---------------- rerank stage 2: reduce 32 k-slices per uncertain row ----------------
__global__ void k_rr2(const ull* __restrict__ partial,
                      const int* __restrict__ ulist,
                      const int* __restrict__ cnt,
                      int* __restrict__ idx_l,
                      float* __restrict__ codes,
                      int level)
{
    const int n = *cnt;
    for (int i = blockIdx.x * 256 + threadIdx.x; i < n; i += gridDim.x * 256) {
        const ull* p = &partial[(size_t)i * 32];
        ull b = p[0];
        #pragma unroll
        for (int s2 = 1; s2 < 32; ++s2) { const ull v = p[s2]; if (v < b) b = v; }
        const int k = (int)(b & 0xffffffffull);
        const int row = ulist[i];
        idx_l[row] = k;
        codes[(size_t)row * NL + level] = (float)k;
    }
}

// ---------------- finalize: quantized = fadd chain q0+q1+q2+q3 (reference order) ----------------
__global__ void k_finalize(const float* __restrict__ cb, const int* __restrict__ idx_hist,
                           float4* __restrict__ outq) {
    const int i = blockIdx.x * 256 + threadIdx.x;
    const int r = i >> 6, c = i & 63;
    const float4* cb4 = (const float4*)cb;
    const int i0 = idx_hist[r];
    const int i1 = idx_hist[NB + r];
    const int i2 = idx_hist[2 * NB + r];
    const int i3 = idx_hist[3 * NB + r];
    float4 q = cb4[(size_t)i0 * 64 + c];
    float4 t1 = cb4[(size_t)(NK + i1) * 64 + c];
    q.x = __fadd_rn(q.x, t1.x); q.y = __fadd_rn(q.y, t1.y);
    q.z = __fadd_rn(q.z, t1.z); q.w = __fadd_rn(q.w, t1.w);
    float4 t2 = cb4[(size_t)(2 * NK + i2) * 64 + c];
    q.x = __fadd_rn(q.x, t2.x); q.y = __fadd_rn(q.y, t2.y);
    q.z = __fadd_rn(q.z, t2.z); q.w = __fadd_rn(q.w, t2.w);
    float4 t3 = cb4[(size_t)(3 * NK + i3) * 64 + c];
    q.x = __fadd_rn(q.x, t3.x); q.y = __fadd_rn(q.y, t3.y);
    q.z = __fadd_rn(q.z, t3.z); q.w = __fadd_rn(q.w, t3.w);
    outq[i] = q;
}

extern "C" void kernel_launch(void* const* d_in, const int* in_sizes, int n_in,
                              void* d_out, int out_size, void* d_ws, size_t ws_size,
                              hipStream_t stream) {
    const float* residual = (const float*)d_in[0];
    const float* cb = (const float*)d_in[1];

    ull* pb = (ull*)d_ws;                                        // [2][B]  1 MB
    float* ps2 = (float*)(pb + 2 * (size_t)NB);                  // [2][B]  512 KB
    ull* partial = (ull*)(ps2 + 2 * (size_t)NB);                 // 16.8 MB
    float* e2 = (float*)(partial + (size_t)(NB + 16) * 32);      // 32 KB
    int* idx_hist = (int*)(e2 + NL * NK);                        // [L][B] 1 MB
    int* ulist = idx_hist + (size_t)NL * NB;                     // 256 KB
    int* cnt = ulist + NB;
    unsigned short* ehf = (unsigned short*)(cnt + 64);           // fp16 frag-major 4 MB

    float* codes = (float*)d_out + (size_t)NB * ND;              // fp32 [B, L]

    k_zero<<<1, 64, 0, stream>>>(cnt);
    k_e2<<<NL * NK / 32, 64, 0, stream>>>(cb, e2);
    k_split16<<<NL * NK * 32 / 256, 256, 0, stream>>>(cb, ehf);

    for (int l = 0; l < NL; ++l) {
        const unsigned short* ehl = ehf + (size_t)l * NK * ND;
        const float* e2l = e2 + (size_t)l * NK;
        int* idx_l = idx_hist + (size_t)l * NB;
        k_passA<<<NB / 128 * 2, 256, 0, stream>>>(residual, cb, ehl, e2l, idx_hist, pb, ps2, l);
        k_margin<<<NB / 256, 256, 0, stream>>>(pb, ps2, idx_l, codes, ulist, cnt + l, l);
        k_rr1<<<2048, 256, 0, stream>>>(residual, cb, cb + (size_t)l * NK * ND, e2l,
                                        idx_hist, ulist, cnt + l, partial, l);
        k_rr2<<<64, 256, 0, stream>>>(partial, ulist, cnt + l, idx_l, codes, l);
    }
    k_finalize<<<NB * ND / 4 / 256, 256, 0, stream>>>(cb, idx_hist, (float4*)d_out);
}

// Round 6
// 1451.330 us; speedup vs baseline: 13.3305x; 13.3305x over previous
//
#include <hip/hip_runtime.h>
#include <stdint.h>

#define NB 65536      // B rows
#define ND 256        // D
#define NK 2048       // K
#define NL 4          // L
#define THRM 0.012f   // accept margin for fp16 screening (score err max ~5e-3)

typedef _Float16 v8h __attribute__((ext_vector_type(8)));   // 8 fp16 (4 VGPR)
typedef __attribute__((ext_vector_type(4))) float v4f;      // MFMA acc
typedef unsigned long long ull;

// ---------------- zero the per-level uncertain counters ----------------
__global__ void k_zero(int* __restrict__ cnt) {
    if (threadIdx.x < NL) cnt[threadIdx.x] = 0;
}

// ---------------- e2: numpy-pairwise sum of emb^2 per row (validated r2) ----------------
__global__ void k_e2(const float* __restrict__ cb, float* __restrict__ e2) {
    __shared__ float tile[32 * 260];
    const int rowbase = blockIdx.x * 32;
    const float4* cb4 = (const float4*)(cb + (size_t)rowbase * ND);
    for (int it = 0; it < 32; ++it) {
        float4 v = cb4[it * 64 + threadIdx.x];
        *(float4*)&tile[it * 260 + threadIdx.x * 4] = v;
    }
    __syncthreads();
    if (threadIdx.x < 32) {
        const float* a = &tile[threadIdx.x * 260];
        float halves[2];
        for (int h = 0; h < 2; ++h) {
            const float* p = a + h * 128;
            float r8[8];
            #pragma unroll
            for (int j = 0; j < 8; ++j) r8[j] = __fmul_rn(p[j], p[j]);
            for (int i = 8; i < 128; i += 8) {
                #pragma unroll
                for (int j = 0; j < 8; ++j) r8[j] = __fadd_rn(r8[j], __fmul_rn(p[i + j], p[i + j]));
            }
            halves[h] = __fadd_rn(__fadd_rn(__fadd_rn(r8[0], r8[1]), __fadd_rn(r8[2], r8[3])),
                                  __fadd_rn(__fadd_rn(r8[4], r8[5]), __fadd_rn(r8[6], r8[7])));
        }
        e2[rowbase + threadIdx.x] = __fadd_rn(halves[0], halves[1]);
    }
}

// ---------------- convert codebooks to fp16 fragment-major ----------------
__global__ void k_split16(const float* __restrict__ cb, unsigned short* __restrict__ ehf) {
    const int f = blockIdx.x * 256 + threadIdx.x;     // 0 .. L*K*32
    const int g = f & 31;
    const int k = (f >> 5) & (NK - 1);
    const int l = f >> 16;
    const float* p = cb + ((size_t)(l * NK + k) * ND + g * 8);
    float4 a = *(const float4*)p;
    float4 b = *(const float4*)(p + 4);
    v8h h;
    h[0] = (_Float16)a.x; h[1] = (_Float16)a.y; h[2] = (_Float16)a.z; h[3] = (_Float16)a.w;
    h[4] = (_Float16)b.x; h[5] = (_Float16)b.y; h[6] = (_Float16)b.z; h[7] = (_Float16)b.w;
    const size_t u = (size_t)(k >> 4) * 512 + (g >> 2) * 64 + (g & 3) * 16 + (k & 15);
    *(v8h*)(void*)(ehf + (size_t)l * (NK * ND) + u * 8) = h;
}

// ---------------- pass A: fp16 MFMA screening + best/second argmin, split-K x2 ----------------
__global__ __launch_bounds__(256, 3)
void k_passA(const float* __restrict__ residual,
             const float* __restrict__ cb,
             const unsigned short* __restrict__ ehf,
             const float* __restrict__ e2,
             const int* __restrict__ idx_hist,
             float* __restrict__ pb1,                  // [2][B] best score
             int* __restrict__ pk1,                    // [2][B] best k
             float* __restrict__ ps2,                  // [2][B] second best
             int level)
{
    __shared__ unsigned short btile[2][8192];

    const int tid = threadIdx.x;
    const int w = tid >> 6;
    const int lane = tid & 63;
    const int kloc = lane & 15;
    const int quad = lane >> 4;
    const int half = blockIdx.x & 1;
    const int rowbase = (blockIdx.x >> 1) * 128 + w * 32;

    v8h ah[2][8];
    #pragma unroll
    for (int m = 0; m < 2; ++m) {
        const int row = rowbase + m * 16 + kloc;
        const float* rp = residual + (size_t)row * ND;
        int pk[NL];
        for (int j = 0; j < level; ++j) pk[j] = idx_hist[j * NB + row];
        #pragma unroll
        for (int dc = 0; dc < 8; ++dc) {
            const int d0 = dc * 32 + quad * 8;
            float buf[8];
            *(float4*)&buf[0] = *(const float4*)(rp + d0);
            *(float4*)&buf[4] = *(const float4*)(rp + d0 + 4);
            for (int j = 0; j < level; ++j) {
                const float* qp = cb + ((size_t)(j * NK + pk[j]) * ND + d0);
                #pragma unroll
                for (int c = 0; c < 8; ++c) buf[c] = __fsub_rn(buf[c], qp[c]);
            }
            #pragma unroll
            for (int c = 0; c < 8; ++c) ah[m][dc][c] = (_Float16)buf[c];
        }
    }

    float b1[8], b2[8];
    int k1[8];
    #pragma unroll
    for (int s = 0; s < 8; ++s) { b1[s] = 1e30f; b2[s] = 1e30f; k1[s] = 0; }

    const uint4* src = (const uint4*)(ehf + (size_t)half * (1024 * ND));
    uint4 pf[4];
    #pragma unroll
    for (int i = 0; i < 4; ++i) pf[i] = src[i * 256 + tid];
    {
        uint4* dst = (uint4*)&btile[0][0];
        #pragma unroll
        for (int i = 0; i < 4; ++i) dst[i * 256 + tid] = pf[i];
    }
    #pragma unroll
    for (int i = 0; i < 4; ++i) pf[i] = src[1024 + i * 256 + tid];
    __syncthreads();

    #pragma unroll 1
    for (int kt = 0; kt < 32; ++kt) {
        const int b = kt & 1;
        #pragma unroll
        for (int nt = 0; nt < 2; ++nt) {
            const int kglob = half * 1024 + kt * 32 + nt * 16 + kloc;
            const float e2v = e2[kglob];
            v4f a0a = {0.f,0.f,0.f,0.f}, a0b = {0.f,0.f,0.f,0.f};
            v4f a1a = {0.f,0.f,0.f,0.f}, a1b = {0.f,0.f,0.f,0.f};
            #pragma unroll
            for (int dc = 0; dc < 4; ++dc) {
                const v8h bh = *(const v8h*)(void*)&btile[b][((nt * 8 + dc) * 64 + quad * 16 + kloc) * 8];
                a0a = __builtin_amdgcn_mfma_f32_16x16x32_f16(ah[0][dc], bh, a0a, 0, 0, 0);
                a1a = __builtin_amdgcn_mfma_f32_16x16x32_f16(ah[1][dc], bh, a1a, 0, 0, 0);
            }
            #pragma unroll
            for (int dc = 4; dc < 8; ++dc) {
                const v8h bh = *(const v8h*)(void*)&btile[b][((nt * 8 + dc) * 64 + quad * 16 + kloc) * 8];
                a0b = __builtin_amdgcn_mfma_f32_16x16x32_f16(ah[0][dc], bh, a0b, 0, 0, 0);
                a1b = __builtin_amdgcn_mfma_f32_16x16x32_f16(ah[1][dc], bh, a1b, 0, 0, 0);
            }
            #pragma unroll
            for (int reg = 0; reg < 4; ++reg) {
                const float s0 = __fmaf_rn(-2.0f, a0a[reg] + a0b[reg], e2v);
                if (s0 < b1[reg])      { b2[reg] = b1[reg]; b1[reg] = s0; k1[reg] = kglob; }
                else if (s0 < b2[reg]) { b2[reg] = s0; }
                const float s1 = __fmaf_rn(-2.0f, a1a[reg] + a1b[reg], e2v);
                if (s1 < b1[4 + reg])      { b2[4 + reg] = b1[4 + reg]; b1[4 + reg] = s1; k1[4 + reg] = kglob; }
                else if (s1 < b2[4 + reg]) { b2[4 + reg] = s1; }
            }
        }
        {
            uint4* dst = (uint4*)&btile[1 - b][0];
            #pragma unroll
            for (int i = 0; i < 4; ++i) dst[i * 256 + tid] = pf[i];
        }
        if (kt + 2 < 32) {
            #pragma unroll
            for (int i = 0; i < 4; ++i) pf[i] = src[(size_t)(kt + 2) * 1024 + i * 256 + tid];
        }
        __syncthreads();
    }

    #pragma unroll
    for (int off = 1; off < 16; off <<= 1) {
        #pragma unroll
        for (int s = 0; s < 8; ++s) {
            float o1 = __shfl_xor(b1[s], off, 16);
            float o2 = __shfl_xor(b2[s], off, 16);
            int   ok = __shfl_xor(k1[s], off, 16);
            float n1 = fminf(b1[s], o1);
            float hi = fmaxf(b1[s], o1);
            float n2 = fminf(fminf(b2[s], o2), hi);
            int   nk = (o1 < b1[s]) ? ok : k1[s];
            b1[s] = n1; b2[s] = n2; k1[s] = nk;
        }
    }
    if (kloc == 0) {
        #pragma unroll
        for (int s = 0; s < 8; ++s) {
            const int m = s >> 2, reg = s & 3;
            const int row = rowbase + m * 16 + quad * 4 + reg;
            pb1[(size_t)half * NB + row] = b1[s];
            pk1[(size_t)half * NB + row] = k1[s];
            ps2[(size_t)half * NB + row] = b2[s];
        }
    }
}

// ---------------- merge K-halves (float compares — scores can be negative!) ----------------
__global__ void k_margin(const float* __restrict__ pb1, const int* __restrict__ pk1,
                         const float* __restrict__ ps2,
                         int* __restrict__ idx_l, float* __restrict__ codes,
                         int* __restrict__ ulist, int* __restrict__ cnt, int level)
{
    const int row = blockIdx.x * 256 + threadIdx.x;
    const float b1a = pb1[row], b1b = pb1[NB + row];
    const int   k1a = pk1[row], k1b = pk1[NB + row];
    // tie -> half 0 (its ks are lower) = first-index semantics
    float b1; int k;
    if (b1b < b1a) { b1 = b1b; k = k1b; } else { b1 = b1a; k = k1a; }
    const float b2 = fminf(fminf(ps2[row], ps2[NB + row]), fmaxf(b1a, b1b));
    idx_l[row] = k;
    codes[(size_t)row * NL + level] = (float)k;
    if (b2 - b1 <= THRM) {
        int p = atomicAdd(cnt, 1);
        ulist[p] = row;
    }
}

// ---------------- rerank stage 1: exact scores (bit-exact validated path) ----------------
__global__ __launch_bounds__(256)
void k_rr1(const float* __restrict__ residual,
           const float* __restrict__ cb,
           const float* __restrict__ emb,
           const float* __restrict__ e2,
           const int* __restrict__ idx_hist,
           const int* __restrict__ ulist,
           const int* __restrict__ cnt,
           ull* __restrict__ partial,
           int level)
{
    __shared__ float embL[64 * 260];
    __shared__ float resL[16 * 260];
    __shared__ float x2s[16];
    __shared__ int   urows[16];
    __shared__ ull   redM[16][17];

    const int t = threadIdx.x;
    const int ks = blockIdx.x & 31;
    const int rt0 = blockIdx.x >> 5;
    const int n = *cnt;
    const int nrt = (n + 15) >> 4;
    if (rt0 >= nrt) return;

    #pragma unroll
    for (int i = 0; i < 16; ++i) {
        const int fi = t + 256 * i;
        const int r = fi >> 6, q = fi & 63;
        *(float4*)&embL[r * 260 + q * 4] = *(const float4*)&emb[(size_t)(ks * 64 + r) * ND + q * 4];
    }
    const int row = t & 15;
    const int kg = t >> 4;
    float e2r[4];
    #pragma unroll
    for (int j = 0; j < 4; ++j) e2r[j] = e2[ks * 64 + kg * 4 + j];

    for (int rt = rt0; rt < nrt; rt += 64) {
        __syncthreads();
        if (t < 16) {
            const int i = rt * 16 + t;
            urows[t] = ulist[(i < n) ? i : rt * 16];
        }
        __syncthreads();
        #pragma unroll
        for (int i = 0; i < 4; ++i) {
            const int fi = t + 256 * i;
            const int r = fi >> 6, q = fi & 63;
            const int ur = urows[r];
            float4 v = ((const float4*)residual)[(size_t)ur * 64 + q];
            for (int j = 0; j < level; ++j) {
                const int kp = idx_hist[j * NB + ur];
                const float4 qv = ((const float4*)cb)[(size_t)(j * NK + kp) * 64 + q];
                v.x = __fsub_rn(v.x, qv.x);
                v.y = __fsub_rn(v.y, qv.y);
                v.z = __fsub_rn(v.z, qv.z);
                v.w = __fsub_rn(v.w, qv.w);
            }
            *(float4*)&resL[r * 260 + q * 4] = v;
        }
        __syncthreads();
        if (t < 16) {
            const float* a = &resL[t * 260];
            float halves[2];
            for (int h = 0; h < 2; ++h) {
                const float* p = a + h * 128;
                float r8[8];
                #pragma unroll
                for (int j = 0; j < 8; ++j) r8[j] = __fmul_rn(p[j], p[j]);
                for (int i = 8; i < 128; i += 8) {
                    #pragma unroll
                    for (int j = 0; j < 8; ++j) r8[j] = __fadd_rn(r8[j], __fmul_rn(p[i + j], p[i + j]));
                }
                halves[h] = __fadd_rn(__fadd_rn(__fadd_rn(r8[0], r8[1]), __fadd_rn(r8[2], r8[3])),
                                      __fadd_rn(__fadd_rn(r8[4], r8[5]), __fadd_rn(r8[6], r8[7])));
            }
            x2s[t] = __fadd_rn(halves[0], halves[1]);
        }
        __syncthreads();

        float d0 = 0.f, d1 = 0.f, d2 = 0.f, d3 = 0.f;
        const float* rp = &resL[row * 260];
        const float* ep = &embL[(kg * 4) * 260];
        #pragma unroll 8
        for (int q = 0; q < 64; ++q) {
            const float4 rv = *(const float4*)&rp[q * 4];
            const float4 e0 = *(const float4*)&ep[q * 4];
            const float4 e1 = *(const float4*)&ep[260 + q * 4];
            const float4 ee2 = *(const float4*)&ep[520 + q * 4];
            const float4 e3 = *(const float4*)&ep[780 + q * 4];
            d0 = __fmaf_rn(rv.x, e0.x, d0); d0 = __fmaf_rn(rv.y, e0.y, d0);
            d0 = __fmaf_rn(rv.z, e0.z, d0); d0 = __fmaf_rn(rv.w, e0.w, d0);
            d1 = __fmaf_rn(rv.x, e1.x, d1); d1 = __fmaf_rn(rv.y, e1.y, d1);
            d1 = __fmaf_rn(rv.z, e1.z, d1); d1 = __fmaf_rn(rv.w, e1.w, d1);
            d2 = __fmaf_rn(rv.x, ee2.x, d2); d2 = __fmaf_rn(rv.y, ee2.y, d2);
            d2 = __fmaf_rn(rv.z, ee2.z, d2); d2 = __fmaf_rn(rv.w, ee2.w, d2);
            d3 = __fmaf_rn(rv.x, e3.x, d3); d3 = __fmaf_rn(rv.y, e3.y, d3);
            d3 = __fmaf_rn(rv.z, e3.z, d3); d3 = __fmaf_rn(rv.w, e3.w, d3);
        }

        const float x2v = x2s[row];
        const int kb = ks * 64 + kg * 4;
        float s;
        ull best, u;
        s = __fsub_rn(__fadd_rn(x2v, e2r[0]), __fmul_rn(2.0f, d0));
        best = ((ull)__float_as_uint(s) << 32) | (ull)(kb + 0);
        s = __fsub_rn(__fadd_rn(x2v, e2r[1]), __fmul_rn(2.0f, d1));
        u = ((ull)__float_as_uint(s) << 32) | (ull)(kb + 1);
        if (u < best) best = u;
        s = __fsub_rn(__fadd_rn(x2v, e2r[2]), __fmul_rn(2.0f, d2));
        u = ((ull)__float_as_uint(s) << 32) | (ull)(kb + 2);
        if (u < best) best = u;
        s = __fsub_rn(__fadd_rn(x2v, e2r[3]), __fmul_rn(2.0f, d3));
        u = ((ull)__float_as_uint(s) << 32) | (ull)(kb + 3);
        if (u < best) best = u;

        redM[row][kg] = best;
        __syncthreads();
        if (t < 16) {
            ull b = redM[t][0];
            #pragma unroll
            for (int g = 1; g < 16; ++g) { const ull v = redM[t][g]; if (v < b) b = v; }
            partial[(size_t)(rt * 16 + t) * 32 + ks] = b;
        }
    }
}

// ---------------- rerank stage 2: reduce 32 k-slices per uncertain row ----------------
__global__ void k_rr2(const ull* __restrict__ partial,
                      const int* __restrict__ ulist,
                      const int* __restrict__ cnt,
                      int* __restrict__ idx_l,
                      float* __restrict__ codes,
                      int level)
{
    const int n = *cnt;
    for (int i = blockIdx.x * 256 + threadIdx.x; i < n; i += gridDim.x * 256) {
        const ull* p = &partial[(size_t)i * 32];
        ull b = p[0];
        #pragma unroll
        for (int s2 = 1; s2 < 32; ++s2) { const ull v = p[s2]; if (v < b) b = v; }
        const int k = (int)(b & 0xffffffffull);
        const int row = ulist[i];
        idx_l[row] = k;
        codes[(size_t)row * NL + level] = (float)k;
    }
}

// ---------------- finalize: quantized = fadd chain q0+q1+q2+q3 (reference order) ----------------
__global__ void k_finalize(const float* __restrict__ cb, const int* __restrict__ idx_hist,
                           float4* __restrict__ outq) {
    const int i = blockIdx.x * 256 + threadIdx.x;
    const int r = i >> 6, c = i & 63;
    const float4* cb4 = (const float4*)cb;
    const int i0 = idx_hist[r];
    const int i1 = idx_hist[NB + r];
    const int i2 = idx_hist[2 * NB + r];
    const int i3 = idx_hist[3 * NB + r];
    float4 q = cb4[(size_t)i0 * 64 + c];
    float4 t1 = cb4[(size_t)(NK + i1) * 64 + c];
    q.x = __fadd_rn(q.x, t1.x); q.y = __fadd_rn(q.y, t1.y);
    q.z = __fadd_rn(q.z, t1.z); q.w = __fadd_rn(q.w, t1.w);
    float4 t2 = cb4[(size_t)(2 * NK + i2) * 64 + c];
    q.x = __fadd_rn(q.x, t2.x); q.y = __fadd_rn(q.y, t2.y);
    q.z = __fadd_rn(q.z, t2.z); q.w = __fadd_rn(q.w, t2.w);
    float4 t3 = cb4[(size_t)(3 * NK + i3) * 64 + c];
    q.x = __fadd_rn(q.x, t3.x); q.y = __fadd_rn(q.y, t3.y);
    q.z = __fadd_rn(q.z, t3.z); q.w = __fadd_rn(q.w, t3.w);
    outq[i] = q;
}

extern "C" void kernel_launch(void* const* d_in, const int* in_sizes, int n_in,
                              void* d_out, int out_size, void* d_ws, size_t ws_size,
                              hipStream_t stream) {
    const float* residual = (const float*)d_in[0];
    const float* cb = (const float*)d_in[1];

    float* pb1 = (float*)d_ws;                                   // [2][B] 512 KB
    int* pk1 = (int*)(pb1 + 2 * (size_t)NB);                     // [2][B] 512 KB
    float* ps2 = (float*)(pk1 + 2 * (size_t)NB);                 // [2][B] 512 KB
    ull* partial = (ull*)(ps2 + 2 * (size_t)NB);                 // 16.8 MB
    float* e2 = (float*)(partial + (size_t)(NB + 16) * 32);      // 32 KB
    int* idx_hist = (int*)(e2 + NL * NK);                        // [L][B] 1 MB
    int* ulist = idx_hist + (size_t)NL * NB;                     // 256 KB
    int* cnt = ulist + NB;
    unsigned short* ehf = (unsigned short*)(cnt + 64);           // fp16 frag-major 4 MB

    float* codes = (float*)d_out + (size_t)NB * ND;              // fp32 [B, L]

    k_zero<<<1, 64, 0, stream>>>(cnt);
    k_e2<<<NL * NK / 32, 64, 0, stream>>>(cb, e2);
    k_split16<<<NL * NK * 32 / 256, 256, 0, stream>>>(cb, ehf);

    for (int l = 0; l < NL; ++l) {
        const unsigned short* ehl = ehf + (size_t)l * NK * ND;
        const float* e2l = e2 + (size_t)l * NK;
        int* idx_l = idx_hist + (size_t)l * NB;
        k_passA<<<NB / 128 * 2, 256, 0, stream>>>(residual, cb, ehl, e2l, idx_hist,
                                                  pb1, pk1, ps2, l);
        k_margin<<<NB / 256, 256, 0, stream>>>(pb1, pk1, ps2, idx_l, codes, ulist, cnt + l, l);
        k_rr1<<<2048, 256, 0, stream>>>(residual, cb, cb + (size_t)l * NK * ND, e2l,
                                        idx_hist, ulist, cnt + l, partial, l);
        k_rr2<<<64, 256, 0, stream>>>(partial, ulist, cnt + l, idx_l, codes, l);
    }
    k_finalize<<<NB * ND / 4 / 256, 256, 0, stream>>>(cb, idx_hist, (float4*)d_out);
}